// Round 2
// baseline (5755.426 us; speedup 1.0000x reference)
//
#include <hip/hip_runtime.h>

// BiLSTM: T=16384 tokens = 128 segs x 128, D=1024, H=512, bidirectional.
//  1) cast X -> bf16; pack W_ih_f|W_ih_b -> bf16 [4096][1024]; bias concat.
//  2) MFMA GEMM: XP[16384][4096] = X @ Wcat^T + bias  (bf16 in, fp32 acc, bf16 out)
//  3) ONE persistent recurrence kernel (cooperative): W_hh resident in LDS,
//     MFMA h@W_hh^T, c in registers, h exchanged via pre-swizzled global bf16
//     double buffer, per-group (32-block) atomic barrier + threadfence per step.
//  4) boundaries as floats to d_out tail.

typedef __attribute__((ext_vector_type(8))) short bf16x8;
typedef __attribute__((ext_vector_type(4))) float f32x4;

__device__ __forceinline__ unsigned short f2bf(float f) {
  unsigned int x = __builtin_bit_cast(unsigned int, f);
  x += 0x7fffu + ((x >> 16) & 1u);
  return (unsigned short)(x >> 16);
}
__device__ __forceinline__ float bf2f(unsigned short u) {
  unsigned int x = ((unsigned int)u) << 16;
  return __builtin_bit_cast(float, x);
}
__device__ __forceinline__ float sigm(float x) { return 1.f / (1.f + __expf(-x)); }
__device__ __forceinline__ float tanhfast(float x) {
  float e = __expf(2.f * x);
  return 1.f - 2.f / (e + 1.f);
}

__device__ __forceinline__ void gl_lds16(const void* g, void* l) {
  __builtin_amdgcn_global_load_lds((const __attribute__((address_space(1))) unsigned int*)g,
                                   (__attribute__((address_space(3))) unsigned int*)l, 16, 0, 0);
}

// ---------------- cast X to bf16 ----------------
__global__ __launch_bounds__(256) void cast_x(const float* __restrict__ X,
                                              unsigned short* __restrict__ Xb) {
  const int i = blockIdx.x * 256 + threadIdx.x;  // float4 index, total 4194304
  const float4 v = ((const float4*)X)[i];
  uint2 o;
  o.x = (unsigned int)f2bf(v.x) | ((unsigned int)f2bf(v.y) << 16);
  o.y = (unsigned int)f2bf(v.z) | ((unsigned int)f2bf(v.w) << 16);
  ((uint2*)Xb)[i] = o;
}

// ---------------- pack W_ih (concat dirs) to bf16 + bias ----------------
__global__ __launch_bounds__(256) void pack_w(const float* __restrict__ Wif,
                                              const float* __restrict__ bf_,
                                              const float* __restrict__ Wib,
                                              const float* __restrict__ bb_,
                                              unsigned short* __restrict__ Wc,
                                              float* __restrict__ biasp) {
  const int pr = blockIdx.x;  // 0..4095
  const int d = pr >> 11, r = pr & 2047;
  const float* src = (d ? Wib : Wif) + (size_t)r * 1024;
  const int t = threadIdx.x;
  const float4 v = ((const float4*)src)[t];
  uint2 o;
  o.x = (unsigned int)f2bf(v.x) | ((unsigned int)f2bf(v.y) << 16);
  o.y = (unsigned int)f2bf(v.z) | ((unsigned int)f2bf(v.w) << 16);
  ((uint2*)(Wc + (size_t)pr * 1024))[t] = o;
  if (t == 0) biasp[pr] = (d ? bb_ : bf_)[r];
}

// ---------------- MFMA GEMM: XP = Xb @ Wc^T + bias ----------------
__global__ __launch_bounds__(256) void gemm_xp(const unsigned short* __restrict__ A,
                                               const unsigned short* __restrict__ B,
                                               const float* __restrict__ bias,
                                               unsigned short* __restrict__ C) {
  __shared__ unsigned short As[128 * 32];
  __shared__ unsigned short Bs[128 * 32];
  const int tid = threadIdx.x;
  const int lane = tid & 63;
  const int wid = tid >> 6;
  const int wm = wid >> 1, wn = wid & 1;
  const long brow = (long)blockIdx.x * 128;
  const long bcol = (long)blockIdx.y * 128;

  f32x4 acc[4][4];
  const f32x4 z = {0.f, 0.f, 0.f, 0.f};
#pragma unroll
  for (int i = 0; i < 4; ++i)
#pragma unroll
    for (int j = 0; j < 4; ++j) acc[i][j] = z;

  const int r16a = wid * 2, r16b = wid * 2 + 1;
  const int srow = lane >> 2;
  const int scol = (lane & 3) * 8;
  const unsigned short* ga0 = A + (brow + r16a * 16 + srow) * 1024 + scol;
  const unsigned short* ga1 = A + (brow + r16b * 16 + srow) * 1024 + scol;
  const unsigned short* gb0 = B + (bcol + r16a * 16 + srow) * 1024 + scol;
  const unsigned short* gb1 = B + (bcol + r16b * 16 + srow) * 1024 + scol;
  unsigned short* la0 = &As[r16a * 512];
  unsigned short* la1 = &As[r16b * 512];
  unsigned short* lb0 = &Bs[r16a * 512];
  unsigned short* lb1 = &Bs[r16b * 512];

  for (int ks = 0; ks < 32; ++ks) {
    const int k0 = ks * 32;
    gl_lds16(ga0 + k0, la0);
    gl_lds16(ga1 + k0, la1);
    gl_lds16(gb0 + k0, lb0);
    gl_lds16(gb1 + k0, lb1);
    __syncthreads();
    bf16x8 av[4], bv[4];
#pragma unroll
    for (int f = 0; f < 4; ++f) {
      av[f] = *(const bf16x8*)&As[(wm * 64 + f * 16 + (lane & 15)) * 32 + (lane >> 4) * 8];
      bv[f] = *(const bf16x8*)&Bs[(wn * 64 + f * 16 + (lane & 15)) * 32 + (lane >> 4) * 8];
    }
#pragma unroll
    for (int fm = 0; fm < 4; ++fm)
#pragma unroll
      for (int fn = 0; fn < 4; ++fn)
        acc[fm][fn] = __builtin_amdgcn_mfma_f32_16x16x32_bf16(av[fm], bv[fn], acc[fm][fn], 0, 0, 0);
    __syncthreads();
  }
  const int crow0 = wm * 64 + (lane >> 4) * 4;
  const int ccol0 = wn * 64 + (lane & 15);
#pragma unroll
  for (int fm = 0; fm < 4; ++fm) {
#pragma unroll
    for (int fn = 0; fn < 4; ++fn) {
      const long col = bcol + ccol0 + fn * 16;
      const float bsv = bias[col];
#pragma unroll
      for (int r = 0; r < 4; ++r) {
        const long row = brow + crow0 + fm * 16 + r;
        C[row * 4096 + col] = f2bf(acc[fm][fn][r] + bsv);
      }
    }
  }
}

// ---------------- persistent recurrence ----------------
// grid 256 x block 256. Block = (dir, ct: 32-chain tile, ut: 16-unit tile).
// W_s: [64 rows = gate*16+u][512 k] bf16, XOR-swizzled, resident all steps.
// A_s: [32 chains][512 k] bf16, staged per step from pre-swizzled global hbuf.
// Wave w: wh=w&1 chain-half (16 chains), kq=w>>1 K-half (256 k).
// Lane (gate waves kq=0): unit u=lane&15, chains (lane>>4)*4+r; gates = frag idx.
// c state: 4 floats/lane in registers for the whole kernel.
__global__ __launch_bounds__(256, 1) void lstm_persist(
    const unsigned short* __restrict__ XPb, const float* __restrict__ Whf,
    const float* __restrict__ Whb, unsigned short* __restrict__ hb0,
    unsigned short* __restrict__ hb1, float* __restrict__ out,
    unsigned int* __restrict__ ctr) {
  __shared__ unsigned short W_s[32768];  // 64 KB
  __shared__ unsigned short A_s[16384];  // 32 KB
  __shared__ float P_s[2][64][20];       // 10 KB, padded stride 20

  const int tid = threadIdx.x;
  const int bid = blockIdx.x;
  const int dir = bid >> 7;
  const int rb = bid & 127;
  const int ct = rb >> 5;
  const int ut = rb & 31;
  const int grp = dir * 4 + ct;
  const int lane = tid & 63;
  const int w = tid >> 6;
  const int wh = w & 1;
  const int kq = w >> 1;

  // ---- W_hh slice -> LDS (bf16, swizzled), once ----
  {
    const float* Wh = dir ? Whb : Whf;
    const int rl = tid >> 2;  // 0..63 = gate*16+u
    const int q = tid & 3;    // k quarter
    const float* src = Wh + (size_t)((rl >> 4) * 512 + ut * 16 + (rl & 15)) * 512 + q * 128;
    char* base = (char*)W_s + rl * 1024;
    const int sw = (rl & 7) << 4;
#pragma unroll
    for (int i = 0; i < 32; ++i) {
      const float4 v = ((const float4*)src)[i];
      const int kb = (q * 128 + i * 4) * 2;
      uint2 o;
      o.x = (unsigned)f2bf(v.x) | ((unsigned)f2bf(v.y) << 16);
      o.y = (unsigned)f2bf(v.z) | ((unsigned)f2bf(v.w) << 16);
      *(uint2*)(base + (kb ^ sw)) = o;
    }
  }
  __syncthreads();

  float c_reg[4] = {0.f, 0.f, 0.f, 0.f};
  const size_t tileoff = (size_t)(dir * 4 + ct) * 32768;  // bytes per (dir,ct) h tile

  for (int tau = 0; tau < 128; ++tau) {
    const unsigned short* hc = (tau & 1) ? hb1 : hb0;
    unsigned short* hn = (tau & 1) ? hb0 : hb1;
    const int tcol = dir ? (127 - tau) : tau;

    // XP prefetch into regs (gate waves): overlaps with h staging below
    unsigned short xpr[16];
    if (kq == 0) {
      const int u_g = ut * 16 + (lane & 15);
#pragma unroll
      for (int r = 0; r < 4; ++r) {
        const int seg = ct * 32 + wh * 16 + (lane >> 4) * 4 + r;
        const size_t tok = (size_t)seg * 128 + tcol;
        const unsigned short* xp = XPb + tok * 4096 + dir * 2048 + u_g;
#pragma unroll
        for (int g = 0; g < 4; ++g) xpr[g * 4 + r] = xp[g * 512];
      }
    }

    // stage h tile (linear copy; buffer is pre-swizzled)
    {
      const char* srcb = (const char*)hc + tileoff;
      char* dstb = (char*)A_s;
#pragma unroll
      for (int j = 0; j < 8; ++j) {
        const int o = (j * 256 + tid) * 16;
        gl_lds16(srcb + o, dstb + o);
      }
    }
    __syncthreads();  // drains vmcnt (stage + xpr) per barrier semantics

    // MFMA: 16 chains x 64 cols x 256 k per wave
    f32x4 acc[4];
    const f32x4 z = {0.f, 0.f, 0.f, 0.f};
    acc[0] = z; acc[1] = z; acc[2] = z; acc[3] = z;
    {
      const int ar = wh * 16 + (lane & 15);
      const char* abase = (const char*)A_s + ar * 1024;
      const int asw = (ar & 7) << 4;
      const int br = lane & 15;
      const char* bbase = (const char*)W_s + br * 1024;
      const int bsw = (br & 7) << 4;
#pragma unroll
      for (int kk = 0; kk < 8; ++kk) {
        const int kb = kq * 512 + kk * 64 + (lane >> 4) * 16;
        const bf16x8 af = *(const bf16x8*)(abase + (kb ^ asw));
#pragma unroll
        for (int fn = 0; fn < 4; ++fn) {
          const bf16x8 bf = *(const bf16x8*)(bbase + fn * 16384 + (kb ^ bsw));
          acc[fn] = __builtin_amdgcn_mfma_f32_16x16x32_bf16(af, bf, acc[fn], 0, 0, 0);
        }
      }
    }

    // K-half reduction
    if (kq == 1) {
#pragma unroll
      for (int fn = 0; fn < 4; ++fn) *(f32x4*)&P_s[wh][lane][fn * 4] = acc[fn];
    }
    __syncthreads();
    if (kq == 0) {
#pragma unroll
      for (int fn = 0; fn < 4; ++fn) {
        const f32x4 p = *(const f32x4*)&P_s[wh][lane][fn * 4];
        acc[fn][0] += p[0]; acc[fn][1] += p[1]; acc[fn][2] += p[2]; acc[fn][3] += p[3];
      }
      // gates: frag fn = gate (i,f,g,o), col = unit, row-reg = chain
      const int u_g = ut * 16 + (lane & 15);
#pragma unroll
      for (int r = 0; r < 4; ++r) {
        const int cl = wh * 16 + (lane >> 4) * 4 + r;  // chain within 32
        const int seg = ct * 32 + cl;
        const size_t tok = (size_t)seg * 128 + tcol;
        const float gi = acc[0][r] + bf2f(xpr[0 + r]);
        const float gf = acc[1][r] + bf2f(xpr[4 + r]);
        const float gg = acc[2][r] + bf2f(xpr[8 + r]);
        const float go = acc[3][r] + bf2f(xpr[12 + r]);
        float cv = sigm(gf) * c_reg[r] + sigm(gi) * tanhfast(gg);
        c_reg[r] = cv;
        const float hv = sigm(go) * tanhfast(cv);
        out[tok * 1024 + dir * 512 + u_g] = hv;
        *(unsigned short*)((char*)hn + tileoff + cl * 1024 + ((u_g * 2) ^ ((cl & 7) << 4))) =
            f2bf(hv);
      }
    }

    // per-group barrier: release h writes, arrive, spin, acquire
    __threadfence();
    __syncthreads();
    if (tid == 0) {
      __hip_atomic_fetch_add(ctr + grp, 1u, __ATOMIC_RELEASE, __HIP_MEMORY_SCOPE_AGENT);
      const unsigned tgt = (unsigned)(tau + 1) * 32u;
      while (__hip_atomic_load(ctr + grp, __ATOMIC_ACQUIRE, __HIP_MEMORY_SCOPE_AGENT) < tgt)
        __builtin_amdgcn_s_sleep(2);
    }
    __syncthreads();
  }
}

// ---------------- boundaries passthrough ----------------
__global__ void wr_bounds(const int* __restrict__ b, float* __restrict__ o) {
  const int i = threadIdx.x;
  if (i < 129) o[i] = (float)b[i];
}

extern "C" void kernel_launch(void* const* d_in, const int* in_sizes, int n_in,
                              void* d_out, int out_size, void* d_ws, size_t ws_size,
                              hipStream_t stream) {
  const float* X = (const float*)d_in[0];
  const int* bnd = (const int*)d_in[1];
  const float* Wif = (const float*)d_in[2];
  const float* Whf = (const float*)d_in[3];
  const float* bf_ = (const float*)d_in[4];
  const float* Wib = (const float*)d_in[5];
  const float* Whb = (const float*)d_in[6];
  const float* bb_ = (const float*)d_in[7];
  float* out = (float*)d_out;

  wr_bounds<<<1, 256, 0, stream>>>(bnd, out + 16777216);

  char* ws = (char*)d_ws;
  const size_t NEED = 176701504ULL;
  if (ws_size < NEED) return;

  unsigned short* XPb = (unsigned short*)(ws + 0);          // 128 MB
  unsigned short* Xb = (unsigned short*)(ws + 134217728);   // 32 MB
  unsigned short* Wc = (unsigned short*)(ws + 167772160);   // 8 MB
  float* biasp = (float*)(ws + 176160768);                  // 16 KB
  unsigned short* hb0 = (unsigned short*)(ws + 176177152);  // 256 KB
  unsigned short* hb1 = (unsigned short*)(ws + 176439296);  // 256 KB
  unsigned int* ctrp = (unsigned int*)(ws + 176701440);     // 64 B

  cast_x<<<16384, 256, 0, stream>>>(X, Xb);
  pack_w<<<4096, 256, 0, stream>>>(Wif, bf_, Wib, bb_, Wc, biasp);
  dim3 gg(128, 32);
  gemm_xp<<<gg, 256, 0, stream>>>(Xb, Wc, biasp, XPb);

  hipMemsetAsync(hb0, 0, 262144, stream);
  hipMemsetAsync(ctrp, 0, 64, stream);

  {
    const unsigned short* xpb = XPb;
    const float* whf = Whf;
    const float* whb = Whb;
    unsigned short* h0 = hb0;
    unsigned short* h1 = hb1;
    float* op = out;
    unsigned int* cp = ctrp;
    void* args[] = {&xpb, &whf, &whb, &h0, &h1, &op, &cp};
    hipError_t e = hipLaunchCooperativeKernel((const void*)lstm_persist, dim3(256), dim3(256),
                                              args, 0, stream);
    if (e != hipSuccess) {
      // fallback: plain launch; 256 blocks @ 1 block/CU on 256 CUs co-reside
      lstm_persist<<<256, 256, 0, stream>>>(XPb, Whf, Whb, hb0, hb1, out, ctrp);
    }
  }
}

// Round 3
// 1751.951 us; speedup vs baseline: 3.2852x; 3.2852x over previous
//
#include <hip/hip_runtime.h>

// BiLSTM: T=16384 tokens = 128 segs x 128, D=1024, H=512, bidirectional.
//  1) cast X -> bf16; pack W_ih_f|W_ih_b -> bf16 [4096][1024]; bias concat.
//  2) MFMA GEMM: XP[16384][4096] = X @ Wcat^T + bias  (bf16 in, fp32 acc, bf16 out)
//  3) ONE persistent recurrence kernel (cooperative): W_hh resident in LDS,
//     MFMA h@W_hh^T, c in registers, h exchanged via pre-swizzled global bf16
//     double buffer. Per-group (32-block) barrier: RMW-release arrival,
//     RELAXED polling (no per-poll cache maintenance!), single acquire fence.
//  4) boundaries as floats to d_out tail.

typedef __attribute__((ext_vector_type(8))) short bf16x8;
typedef __attribute__((ext_vector_type(4))) float f32x4;

__device__ __forceinline__ unsigned short f2bf(float f) {
  unsigned int x = __builtin_bit_cast(unsigned int, f);
  x += 0x7fffu + ((x >> 16) & 1u);
  return (unsigned short)(x >> 16);
}
__device__ __forceinline__ float bf2f(unsigned short u) {
  unsigned int x = ((unsigned int)u) << 16;
  return __builtin_bit_cast(float, x);
}
__device__ __forceinline__ float sigm(float x) { return 1.f / (1.f + __expf(-x)); }
__device__ __forceinline__ float tanhfast(float x) {
  float e = __expf(2.f * x);
  return 1.f - 2.f / (e + 1.f);
}

__device__ __forceinline__ void gl_lds16(const void* g, void* l) {
  __builtin_amdgcn_global_load_lds((const __attribute__((address_space(1))) unsigned int*)g,
                                   (__attribute__((address_space(3))) unsigned int*)l, 16, 0, 0);
}

// ---------------- cast X to bf16 ----------------
__global__ __launch_bounds__(256) void cast_x(const float* __restrict__ X,
                                              unsigned short* __restrict__ Xb) {
  const int i = blockIdx.x * 256 + threadIdx.x;  // float4 index, total 4194304
  const float4 v = ((const float4*)X)[i];
  uint2 o;
  o.x = (unsigned int)f2bf(v.x) | ((unsigned int)f2bf(v.y) << 16);
  o.y = (unsigned int)f2bf(v.z) | ((unsigned int)f2bf(v.w) << 16);
  ((uint2*)Xb)[i] = o;
}

// ---------------- pack W_ih (concat dirs) to bf16 + bias ----------------
__global__ __launch_bounds__(256) void pack_w(const float* __restrict__ Wif,
                                              const float* __restrict__ bf_,
                                              const float* __restrict__ Wib,
                                              const float* __restrict__ bb_,
                                              unsigned short* __restrict__ Wc,
                                              float* __restrict__ biasp) {
  const int pr = blockIdx.x;  // 0..4095
  const int d = pr >> 11, r = pr & 2047;
  const float* src = (d ? Wib : Wif) + (size_t)r * 1024;
  const int t = threadIdx.x;
  const float4 v = ((const float4*)src)[t];
  uint2 o;
  o.x = (unsigned int)f2bf(v.x) | ((unsigned int)f2bf(v.y) << 16);
  o.y = (unsigned int)f2bf(v.z) | ((unsigned int)f2bf(v.w) << 16);
  ((uint2*)(Wc + (size_t)pr * 1024))[t] = o;
  if (t == 0) biasp[pr] = (d ? bb_ : bf_)[r];
}

// ---------------- MFMA GEMM: XP = Xb @ Wc^T + bias ----------------
__global__ __launch_bounds__(256) void gemm_xp(const unsigned short* __restrict__ A,
                                               const unsigned short* __restrict__ B,
                                               const float* __restrict__ bias,
                                               unsigned short* __restrict__ C) {
  __shared__ unsigned short As[128 * 32];
  __shared__ unsigned short Bs[128 * 32];
  const int tid = threadIdx.x;
  const int lane = tid & 63;
  const int wid = tid >> 6;
  const int wm = wid >> 1, wn = wid & 1;
  const long brow = (long)blockIdx.x * 128;
  const long bcol = (long)blockIdx.y * 128;

  f32x4 acc[4][4];
  const f32x4 z = {0.f, 0.f, 0.f, 0.f};
#pragma unroll
  for (int i = 0; i < 4; ++i)
#pragma unroll
    for (int j = 0; j < 4; ++j) acc[i][j] = z;

  const int r16a = wid * 2, r16b = wid * 2 + 1;
  const int srow = lane >> 2;
  const int scol = (lane & 3) * 8;
  const unsigned short* ga0 = A + (brow + r16a * 16 + srow) * 1024 + scol;
  const unsigned short* ga1 = A + (brow + r16b * 16 + srow) * 1024 + scol;
  const unsigned short* gb0 = B + (bcol + r16a * 16 + srow) * 1024 + scol;
  const unsigned short* gb1 = B + (bcol + r16b * 16 + srow) * 1024 + scol;
  unsigned short* la0 = &As[r16a * 512];
  unsigned short* la1 = &As[r16b * 512];
  unsigned short* lb0 = &Bs[r16a * 512];
  unsigned short* lb1 = &Bs[r16b * 512];

  for (int ks = 0; ks < 32; ++ks) {
    const int k0 = ks * 32;
    gl_lds16(ga0 + k0, la0);
    gl_lds16(ga1 + k0, la1);
    gl_lds16(gb0 + k0, lb0);
    gl_lds16(gb1 + k0, lb1);
    __syncthreads();
    bf16x8 av[4], bv[4];
#pragma unroll
    for (int f = 0; f < 4; ++f) {
      av[f] = *(const bf16x8*)&As[(wm * 64 + f * 16 + (lane & 15)) * 32 + (lane >> 4) * 8];
      bv[f] = *(const bf16x8*)&Bs[(wn * 64 + f * 16 + (lane & 15)) * 32 + (lane >> 4) * 8];
    }
#pragma unroll
    for (int fm = 0; fm < 4; ++fm)
#pragma unroll
      for (int fn = 0; fn < 4; ++fn)
        acc[fm][fn] = __builtin_amdgcn_mfma_f32_16x16x32_bf16(av[fm], bv[fn], acc[fm][fn], 0, 0, 0);
    __syncthreads();
  }
  const int crow0 = wm * 64 + (lane >> 4) * 4;
  const int ccol0 = wn * 64 + (lane & 15);
#pragma unroll
  for (int fm = 0; fm < 4; ++fm) {
#pragma unroll
    for (int fn = 0; fn < 4; ++fn) {
      const long col = bcol + ccol0 + fn * 16;
      const float bsv = bias[col];
#pragma unroll
      for (int r = 0; r < 4; ++r) {
        const long row = brow + crow0 + fm * 16 + r;
        C[row * 4096 + col] = f2bf(acc[fm][fn][r] + bsv);
      }
    }
  }
}

// ---------------- persistent recurrence ----------------
// grid 256 x block 256. Block = (dir, ct: 32-chain tile, ut: 16-unit tile).
// W_s: [64 rows = gate*16+u][512 k] bf16, XOR-swizzled, resident all steps.
// A_s: [32 chains][512 k] bf16, staged per step from pre-swizzled global hbuf.
// Wave w: wh=w&1 chain-half (16 chains), kq=w>>1 K-half (256 k).
// c state: 4 floats/lane in registers for the whole kernel.
// Barrier per step: syncthreads (drain) -> tid0 RMW release (one wbl2) ->
// RELAXED poll -> one acquire fence (one inv) -> syncthreads.
__global__ __launch_bounds__(256, 1) void lstm_persist(
    const unsigned short* __restrict__ XPb, const float* __restrict__ Whf,
    const float* __restrict__ Whb, unsigned short* __restrict__ hb0,
    unsigned short* __restrict__ hb1, float* __restrict__ out,
    unsigned int* __restrict__ ctr) {
  __shared__ unsigned short W_s[32768];  // 64 KB
  __shared__ unsigned short A_s[16384];  // 32 KB
  __shared__ float P_s[2][64][20];       // 10 KB, padded stride 20

  const int tid = threadIdx.x;
  const int bid = blockIdx.x;
  const int dir = bid >> 7;
  const int rb = bid & 127;
  const int ct = rb >> 5;
  const int ut = rb & 31;
  const int grp = dir * 4 + ct;
  const int lane = tid & 63;
  const int w = tid >> 6;
  const int wh = w & 1;
  const int kq = w >> 1;
  unsigned int* const myctr = ctr + grp * 32;  // 128B stride: no false sharing

  // ---- W_hh slice -> LDS (bf16, swizzled), once ----
  {
    const float* Wh = dir ? Whb : Whf;
    const int rl = tid >> 2;  // 0..63 = gate*16+u
    const int q = tid & 3;    // k quarter
    const float* src = Wh + (size_t)((rl >> 4) * 512 + ut * 16 + (rl & 15)) * 512 + q * 128;
    char* base = (char*)W_s + rl * 1024;
    const int sw = (rl & 7) << 4;
#pragma unroll
    for (int i = 0; i < 32; ++i) {
      const float4 v = ((const float4*)src)[i];
      const int kb = (q * 128 + i * 4) * 2;
      uint2 o;
      o.x = (unsigned)f2bf(v.x) | ((unsigned)f2bf(v.y) << 16);
      o.y = (unsigned)f2bf(v.z) | ((unsigned)f2bf(v.w) << 16);
      *(uint2*)(base + (kb ^ sw)) = o;
    }
  }
  __syncthreads();

  float c_reg[4] = {0.f, 0.f, 0.f, 0.f};
  const size_t tileoff = (size_t)(dir * 4 + ct) * 32768;  // bytes per (dir,ct) h tile

  for (int tau = 0; tau < 128; ++tau) {
    const unsigned short* hc = (tau & 1) ? hb1 : hb0;
    unsigned short* hn = (tau & 1) ? hb0 : hb1;
    const int tcol = dir ? (127 - tau) : tau;

    // XP prefetch into regs (gate waves): overlaps with h staging below
    unsigned short xpr[16];
    if (kq == 0) {
      const int u_g = ut * 16 + (lane & 15);
#pragma unroll
      for (int r = 0; r < 4; ++r) {
        const int seg = ct * 32 + wh * 16 + (lane >> 4) * 4 + r;
        const size_t tok = (size_t)seg * 128 + tcol;
        const unsigned short* xp = XPb + tok * 4096 + dir * 2048 + u_g;
#pragma unroll
        for (int g = 0; g < 4; ++g) xpr[g * 4 + r] = xp[g * 512];
      }
    }

    // stage h tile (linear copy; buffer is pre-swizzled)
    {
      const char* srcb = (const char*)hc + tileoff;
      char* dstb = (char*)A_s;
#pragma unroll
      for (int j = 0; j < 8; ++j) {
        const int o = (j * 256 + tid) * 16;
        gl_lds16(srcb + o, dstb + o);
      }
    }
    __syncthreads();  // drains vmcnt (stage + xpr) per barrier semantics

    // MFMA: 16 chains x 64 cols x 256 k per wave
    f32x4 acc[4];
    const f32x4 z = {0.f, 0.f, 0.f, 0.f};
    acc[0] = z; acc[1] = z; acc[2] = z; acc[3] = z;
    {
      const int ar = wh * 16 + (lane & 15);
      const char* abase = (const char*)A_s + ar * 1024;
      const int asw = (ar & 7) << 4;
      const int br = lane & 15;
      const char* bbase = (const char*)W_s + br * 1024;
      const int bsw = (br & 7) << 4;
#pragma unroll
      for (int kk = 0; kk < 8; ++kk) {
        const int kb = kq * 512 + kk * 64 + (lane >> 4) * 16;
        const bf16x8 af = *(const bf16x8*)(abase + (kb ^ asw));
#pragma unroll
        for (int fn = 0; fn < 4; ++fn) {
          const bf16x8 bf = *(const bf16x8*)(bbase + fn * 16384 + (kb ^ bsw));
          acc[fn] = __builtin_amdgcn_mfma_f32_16x16x32_bf16(af, bf, acc[fn], 0, 0, 0);
        }
      }
    }

    // K-half reduction
    if (kq == 1) {
#pragma unroll
      for (int fn = 0; fn < 4; ++fn) *(f32x4*)&P_s[wh][lane][fn * 4] = acc[fn];
    }
    __syncthreads();
    if (kq == 0) {
#pragma unroll
      for (int fn = 0; fn < 4; ++fn) {
        const f32x4 p = *(const f32x4*)&P_s[wh][lane][fn * 4];
        acc[fn][0] += p[0]; acc[fn][1] += p[1]; acc[fn][2] += p[2]; acc[fn][3] += p[3];
      }
      // gates: frag fn = gate (i,f,g,o), col = unit, row-reg = chain
      const int u_g = ut * 16 + (lane & 15);
#pragma unroll
      for (int r = 0; r < 4; ++r) {
        const int cl = wh * 16 + (lane >> 4) * 4 + r;  // chain within 32
        const int seg = ct * 32 + cl;
        const size_t tok = (size_t)seg * 128 + tcol;
        const float gi = acc[0][r] + bf2f(xpr[0 + r]);
        const float gf = acc[1][r] + bf2f(xpr[4 + r]);
        const float gg = acc[2][r] + bf2f(xpr[8 + r]);
        const float go = acc[3][r] + bf2f(xpr[12 + r]);
        float cv = sigm(gf) * c_reg[r] + sigm(gi) * tanhfast(gg);
        c_reg[r] = cv;
        const float hv = sigm(go) * tanhfast(cv);
        out[tok * 1024 + dir * 512 + u_g] = hv;
        *(unsigned short*)((char*)hn + tileoff + cl * 1024 + ((u_g * 2) ^ ((cl & 7) << 4))) =
            f2bf(hv);
      }
    }

    // ---- per-group barrier ----
    __syncthreads();  // all block's h stores issued + vmcnt drained
    if (tid == 0) {
      // release: publishes this XCD's dirty lines once (wbl2), then RMW
      __hip_atomic_fetch_add(myctr, 1u, __ATOMIC_RELEASE, __HIP_MEMORY_SCOPE_AGENT);
      const unsigned tgt = (unsigned)(tau + 1) * 32u;
      // RELAXED poll: no cache maintenance per iteration
      while (__hip_atomic_load(myctr, __ATOMIC_RELAXED, __HIP_MEMORY_SCOPE_AGENT) < tgt)
        __builtin_amdgcn_s_sleep(1);
      // acquire once: invalidate stale lines so h loads see fresh data
      __builtin_amdgcn_fence(__ATOMIC_ACQUIRE, "agent");
    }
    __syncthreads();
  }
}

// ---------------- boundaries passthrough ----------------
__global__ void wr_bounds(const int* __restrict__ b, float* __restrict__ o) {
  const int i = threadIdx.x;
  if (i < 129) o[i] = (float)b[i];
}

extern "C" void kernel_launch(void* const* d_in, const int* in_sizes, int n_in,
                              void* d_out, int out_size, void* d_ws, size_t ws_size,
                              hipStream_t stream) {
  const float* X = (const float*)d_in[0];
  const int* bnd = (const int*)d_in[1];
  const float* Wif = (const float*)d_in[2];
  const float* Whf = (const float*)d_in[3];
  const float* bf_ = (const float*)d_in[4];
  const float* Wib = (const float*)d_in[5];
  const float* Whb = (const float*)d_in[6];
  const float* bb_ = (const float*)d_in[7];
  float* out = (float*)d_out;

  wr_bounds<<<1, 256, 0, stream>>>(bnd, out + 16777216);

  char* ws = (char*)d_ws;
  const size_t NEED = 176702464ULL;
  if (ws_size < NEED) return;

  unsigned short* XPb = (unsigned short*)(ws + 0);          // 128 MB
  unsigned short* Xb = (unsigned short*)(ws + 134217728);   // 32 MB
  unsigned short* Wc = (unsigned short*)(ws + 167772160);   // 8 MB
  float* biasp = (float*)(ws + 176160768);                  // 16 KB
  unsigned short* hb0 = (unsigned short*)(ws + 176177152);  // 256 KB
  unsigned short* hb1 = (unsigned short*)(ws + 176439296);  // 256 KB
  unsigned int* ctrp = (unsigned int*)(ws + 176701440);     // 1 KB (8 x 128B)

  cast_x<<<16384, 256, 0, stream>>>(X, Xb);
  pack_w<<<4096, 256, 0, stream>>>(Wif, bf_, Wib, bb_, Wc, biasp);
  dim3 gg(128, 32);
  gemm_xp<<<gg, 256, 0, stream>>>(Xb, Wc, biasp, XPb);

  hipMemsetAsync(hb0, 0, 262144, stream);
  hipMemsetAsync(ctrp, 0, 1024, stream);

  {
    const unsigned short* xpb = XPb;
    const float* whf = Whf;
    const float* whb = Whb;
    unsigned short* h0 = hb0;
    unsigned short* h1 = hb1;
    float* op = out;
    unsigned int* cp = ctrp;
    void* args[] = {&xpb, &whf, &whb, &h0, &h1, &op, &cp};
    hipError_t e = hipLaunchCooperativeKernel((const void*)lstm_persist, dim3(256), dim3(256),
                                              args, 0, stream);
    if (e != hipSuccess) {
      // fallback: plain launch; 256 blocks @ 1 block/CU on 256 CUs co-reside
      lstm_persist<<<256, 256, 0, stream>>>(XPb, Whf, Whb, hb0, hb1, out, ctrp);
    }
  }
}

// Round 4
// 674.873 us; speedup vs baseline: 8.5282x; 2.5960x over previous
//
#include <hip/hip_runtime.h>

// BiLSTM: T=16384 tokens = 128 segs x 128, D=1024, H=512, bidirectional.
//  1) cast X -> bf16; pack W_ih_f|W_ih_b -> bf16 [4096][1024]; bias concat.
//  2) MFMA GEMM: XP[16384][4096] = X @ Wcat^T + bias  (bf16 in, fp32 acc, bf16 out)
//  3) ONE persistent recurrence kernel (cooperative): W_hh resident in LDS,
//     MFMA h@W_hh^T, c in registers. h exchanged via LLC-coherent (sc0|sc1)
//     stores/loads -> NO per-step cache maintenance (no wbl2/inv). Barrier =
//     relaxed monotonic counter per group; groups mapped one-per-XCD (bid&7).
//  4) boundaries as floats to d_out tail.

typedef __attribute__((ext_vector_type(8))) short bf16x8;
typedef __attribute__((ext_vector_type(4))) float f32x4;

__device__ __forceinline__ unsigned short f2bf(float f) {
  unsigned int x = __builtin_bit_cast(unsigned int, f);
  x += 0x7fffu + ((x >> 16) & 1u);
  return (unsigned short)(x >> 16);
}
__device__ __forceinline__ float bf2f(unsigned short u) {
  unsigned int x = ((unsigned int)u) << 16;
  return __builtin_bit_cast(float, x);
}
__device__ __forceinline__ float sigm(float x) { return 1.f / (1.f + __expf(-x)); }
__device__ __forceinline__ float tanhfast(float x) {
  float e = __expf(2.f * x);
  return 1.f - 2.f / (e + 1.f);
}

__device__ __forceinline__ void gl_lds16(const void* g, void* l) {
  __builtin_amdgcn_global_load_lds((const __attribute__((address_space(1))) unsigned int*)g,
                                   (__attribute__((address_space(3))) unsigned int*)l, 16, 0, 0);
}
// LLC-coherent variant: aux = SC0|SC1 (0x11) -> bypass L1/L2, read from LLC.
__device__ __forceinline__ void gl_lds16_llc(const void* g, void* l) {
  __builtin_amdgcn_global_load_lds((const __attribute__((address_space(1))) unsigned int*)g,
                                   (__attribute__((address_space(3))) unsigned int*)l, 16, 0, 17);
}

// ---------------- cast X to bf16 ----------------
__global__ __launch_bounds__(256) void cast_x(const float* __restrict__ X,
                                              unsigned short* __restrict__ Xb) {
  const int i = blockIdx.x * 256 + threadIdx.x;  // float4 index, total 4194304
  const float4 v = ((const float4*)X)[i];
  uint2 o;
  o.x = (unsigned int)f2bf(v.x) | ((unsigned int)f2bf(v.y) << 16);
  o.y = (unsigned int)f2bf(v.z) | ((unsigned int)f2bf(v.w) << 16);
  ((uint2*)Xb)[i] = o;
}

// ---------------- pack W_ih (concat dirs) to bf16 + bias ----------------
__global__ __launch_bounds__(256) void pack_w(const float* __restrict__ Wif,
                                              const float* __restrict__ bf_,
                                              const float* __restrict__ Wib,
                                              const float* __restrict__ bb_,
                                              unsigned short* __restrict__ Wc,
                                              float* __restrict__ biasp) {
  const int pr = blockIdx.x;  // 0..4095
  const int d = pr >> 11, r = pr & 2047;
  const float* src = (d ? Wib : Wif) + (size_t)r * 1024;
  const int t = threadIdx.x;
  const float4 v = ((const float4*)src)[t];
  uint2 o;
  o.x = (unsigned int)f2bf(v.x) | ((unsigned int)f2bf(v.y) << 16);
  o.y = (unsigned int)f2bf(v.z) | ((unsigned int)f2bf(v.w) << 16);
  ((uint2*)(Wc + (size_t)pr * 1024))[t] = o;
  if (t == 0) biasp[pr] = (d ? bb_ : bf_)[r];
}

// ---------------- MFMA GEMM: XP = Xb @ Wc^T + bias ----------------
__global__ __launch_bounds__(256) void gemm_xp(const unsigned short* __restrict__ A,
                                               const unsigned short* __restrict__ B,
                                               const float* __restrict__ bias,
                                               unsigned short* __restrict__ C) {
  __shared__ unsigned short As[128 * 32];
  __shared__ unsigned short Bs[128 * 32];
  const int tid = threadIdx.x;
  const int lane = tid & 63;
  const int wid = tid >> 6;
  const int wm = wid >> 1, wn = wid & 1;
  const long brow = (long)blockIdx.x * 128;
  const long bcol = (long)blockIdx.y * 128;

  f32x4 acc[4][4];
  const f32x4 z = {0.f, 0.f, 0.f, 0.f};
#pragma unroll
  for (int i = 0; i < 4; ++i)
#pragma unroll
    for (int j = 0; j < 4; ++j) acc[i][j] = z;

  const int r16a = wid * 2, r16b = wid * 2 + 1;
  const int srow = lane >> 2;
  const int scol = (lane & 3) * 8;
  const unsigned short* ga0 = A + (brow + r16a * 16 + srow) * 1024 + scol;
  const unsigned short* ga1 = A + (brow + r16b * 16 + srow) * 1024 + scol;
  const unsigned short* gb0 = B + (bcol + r16a * 16 + srow) * 1024 + scol;
  const unsigned short* gb1 = B + (bcol + r16b * 16 + srow) * 1024 + scol;
  unsigned short* la0 = &As[r16a * 512];
  unsigned short* la1 = &As[r16b * 512];
  unsigned short* lb0 = &Bs[r16a * 512];
  unsigned short* lb1 = &Bs[r16b * 512];

  for (int ks = 0; ks < 32; ++ks) {
    const int k0 = ks * 32;
    gl_lds16(ga0 + k0, la0);
    gl_lds16(ga1 + k0, la1);
    gl_lds16(gb0 + k0, lb0);
    gl_lds16(gb1 + k0, lb1);
    __syncthreads();
    bf16x8 av[4], bv[4];
#pragma unroll
    for (int f = 0; f < 4; ++f) {
      av[f] = *(const bf16x8*)&As[(wm * 64 + f * 16 + (lane & 15)) * 32 + (lane >> 4) * 8];
      bv[f] = *(const bf16x8*)&Bs[(wn * 64 + f * 16 + (lane & 15)) * 32 + (lane >> 4) * 8];
    }
#pragma unroll
    for (int fm = 0; fm < 4; ++fm)
#pragma unroll
      for (int fn = 0; fn < 4; ++fn)
        acc[fm][fn] = __builtin_amdgcn_mfma_f32_16x16x32_bf16(av[fm], bv[fn], acc[fm][fn], 0, 0, 0);
    __syncthreads();
  }
  const int crow0 = wm * 64 + (lane >> 4) * 4;
  const int ccol0 = wn * 64 + (lane & 15);
#pragma unroll
  for (int fm = 0; fm < 4; ++fm) {
#pragma unroll
    for (int fn = 0; fn < 4; ++fn) {
      const long col = bcol + ccol0 + fn * 16;
      const float bsv = bias[col];
#pragma unroll
      for (int r = 0; r < 4; ++r) {
        const long row = brow + crow0 + fm * 16 + r;
        C[row * 4096 + col] = f2bf(acc[fm][fn][r] + bsv);
      }
    }
  }
}

// ---------------- persistent recurrence ----------------
// grid 256 x block 256. grp = bid&7 (one group per XCD under round-robin):
// dir = grp>>2, ct = grp&3, ut = bid>>3 (16-unit tile 0..31).
// W_s: [64 rows = gate*16+u][512 k] bf16, XOR-swizzled, resident all steps.
// A_s: [32 chains][512 k] bf16, staged per step from pre-swizzled global hbuf
//      via sc0|sc1 global_load_lds (LLC-coherent, no cache maintenance).
// h stores: packed 8B relaxed-agent atomic stores (sc1 write-through to LLC).
// Barrier: syncthreads (vmcnt drain) -> relaxed fetch_add -> relaxed poll ->
// syncthreads. NO fences, NO wbl2/inv in the loop.
__global__ __launch_bounds__(256, 1) void lstm_persist(
    const unsigned short* __restrict__ XPb, const float* __restrict__ Whf,
    const float* __restrict__ Whb, unsigned short* __restrict__ hb0,
    unsigned short* __restrict__ hb1, float* __restrict__ out,
    unsigned int* __restrict__ ctr) {
  __shared__ unsigned short W_s[32768];   // 64 KB
  __shared__ unsigned short A_s[16384];   // 32 KB
  __shared__ float P_s[2][64][20];        // 10 KB, padded stride 20
  __shared__ unsigned short Hrep[32][16]; // 1 KB h repack for 8B stores

  const int tid = threadIdx.x;
  const int bid = blockIdx.x;
  const int grp = bid & 7;    // one group per XCD (round-robin heuristic)
  const int dir = grp >> 2;
  const int ct = grp & 3;
  const int ut = bid >> 3;
  const int lane = tid & 63;
  const int w = tid >> 6;
  const int wh = w & 1;
  const int kq = w >> 1;
  unsigned int* const myctr = ctr + grp * 32;  // 128B stride: no false sharing

  // ---- W_hh slice -> LDS (bf16, swizzled), once ----
  {
    const float* Wh = dir ? Whb : Whf;
    const int rl = tid >> 2;  // 0..63 = gate*16+u
    const int q = tid & 3;    // k quarter
    const float* src = Wh + (size_t)((rl >> 4) * 512 + ut * 16 + (rl & 15)) * 512 + q * 128;
    char* base = (char*)W_s + rl * 1024;
    const int sw = (rl & 7) << 4;
#pragma unroll
    for (int i = 0; i < 32; ++i) {
      const float4 v = ((const float4*)src)[i];
      const int kb = (q * 128 + i * 4) * 2;
      uint2 o;
      o.x = (unsigned)f2bf(v.x) | ((unsigned)f2bf(v.y) << 16);
      o.y = (unsigned)f2bf(v.z) | ((unsigned)f2bf(v.w) << 16);
      *(uint2*)(base + (kb ^ sw)) = o;
    }
  }
  __syncthreads();

  float c_reg[4] = {0.f, 0.f, 0.f, 0.f};
  const size_t tileoff = (size_t)(dir * 4 + ct) * 32768;  // bytes per (dir,ct) h tile

  for (int tau = 0; tau < 128; ++tau) {
    const unsigned short* hc = (tau & 1) ? hb1 : hb0;
    unsigned short* hn = (tau & 1) ? hb0 : hb1;
    const int tcol = dir ? (127 - tau) : tau;

    // XP prefetch into regs (gate waves): overlaps with h staging below
    unsigned short xpr[16];
    if (kq == 0) {
      const int u_g = ut * 16 + (lane & 15);
#pragma unroll
      for (int r = 0; r < 4; ++r) {
        const int seg = ct * 32 + wh * 16 + (lane >> 4) * 4 + r;
        const size_t tok = (size_t)seg * 128 + tcol;
        const unsigned short* xp = XPb + tok * 4096 + dir * 2048 + u_g;
#pragma unroll
        for (int g = 0; g < 4; ++g) xpr[g * 4 + r] = xp[g * 512];
      }
    }

    // stage h tile from LLC (buffer is pre-swizzled; linear copy)
    {
      const char* srcb = (const char*)hc + tileoff;
      char* dstb = (char*)A_s;
#pragma unroll
      for (int j = 0; j < 8; ++j) {
        const int o = (j * 256 + tid) * 16;
        gl_lds16_llc(srcb + o, dstb + o);
      }
    }
    __syncthreads();  // drains vmcnt (stage + xpr)

    // MFMA: 16 chains x 64 cols x 256 k per wave
    f32x4 acc[4];
    const f32x4 z = {0.f, 0.f, 0.f, 0.f};
    acc[0] = z; acc[1] = z; acc[2] = z; acc[3] = z;
    {
      const int ar = wh * 16 + (lane & 15);
      const char* abase = (const char*)A_s + ar * 1024;
      const int asw = (ar & 7) << 4;
      const int br = lane & 15;
      const char* bbase = (const char*)W_s + br * 1024;
      const int bsw = (br & 7) << 4;
#pragma unroll
      for (int kk = 0; kk < 8; ++kk) {
        const int kb = kq * 512 + kk * 64 + (lane >> 4) * 16;
        const bf16x8 af = *(const bf16x8*)(abase + (kb ^ asw));
#pragma unroll
        for (int fn = 0; fn < 4; ++fn) {
          const bf16x8 bf = *(const bf16x8*)(bbase + fn * 16384 + (kb ^ bsw));
          acc[fn] = __builtin_amdgcn_mfma_f32_16x16x32_bf16(af, bf, acc[fn], 0, 0, 0);
        }
      }
    }

    // K-half reduction
    if (kq == 1) {
#pragma unroll
      for (int fn = 0; fn < 4; ++fn) *(f32x4*)&P_s[wh][lane][fn * 4] = acc[fn];
    }
    __syncthreads();
    if (kq == 0) {
#pragma unroll
      for (int fn = 0; fn < 4; ++fn) {
        const f32x4 p = *(const f32x4*)&P_s[wh][lane][fn * 4];
        acc[fn][0] += p[0]; acc[fn][1] += p[1]; acc[fn][2] += p[2]; acc[fn][3] += p[3];
      }
      // gates: frag fn = gate (i,f,g,o), col = unit, row-reg = chain
      const int u_l = lane & 15;
      const int u_g = ut * 16 + u_l;
#pragma unroll
      for (int r = 0; r < 4; ++r) {
        const int cl = wh * 16 + (lane >> 4) * 4 + r;  // chain within 32
        const int seg = ct * 32 + cl;
        const size_t tok = (size_t)seg * 128 + tcol;
        const float gi = acc[0][r] + bf2f(xpr[0 + r]);
        const float gf = acc[1][r] + bf2f(xpr[4 + r]);
        const float gg = acc[2][r] + bf2f(xpr[8 + r]);
        const float go = acc[3][r] + bf2f(xpr[12 + r]);
        float cv = sigm(gf) * c_reg[r] + sigm(gi) * tanhfast(gg);
        c_reg[r] = cv;
        const float hv = sigm(go) * tanhfast(cv);
        out[tok * 1024 + dir * 512 + u_g] = hv;
        Hrep[cl][u_l] = f2bf(hv);
      }
    }
    __syncthreads();  // Hrep complete

    // packed 8B LLC-coherent h stores (swizzled dest, 8B blocks preserved)
    if (tid < 128) {
      const int cl = tid >> 2, q = tid & 3;
      const unsigned long long v = *(const unsigned long long*)&Hrep[cl][q * 4];
      char* dst = (char*)hn + tileoff + cl * 1024 + ((ut * 32 + q * 8) ^ ((cl & 7) << 4));
      __hip_atomic_store((unsigned long long*)dst, v, __ATOMIC_RELAXED,
                         __HIP_MEMORY_SCOPE_AGENT);
    }

    // ---- per-group barrier (fence-free) ----
    __syncthreads();  // drains vmcnt(0): sc1 stores are at LLC
    if (tid == 0) {
      __hip_atomic_fetch_add(myctr, 1u, __ATOMIC_RELAXED, __HIP_MEMORY_SCOPE_AGENT);
      const unsigned tgt = (unsigned)(tau + 1) * 32u;
      while (__hip_atomic_load(myctr, __ATOMIC_RELAXED, __HIP_MEMORY_SCOPE_AGENT) < tgt)
        __builtin_amdgcn_s_sleep(1);
    }
    __syncthreads();
  }
}

// ---------------- boundaries passthrough ----------------
__global__ void wr_bounds(const int* __restrict__ b, float* __restrict__ o) {
  const int i = threadIdx.x;
  if (i < 129) o[i] = (float)b[i];
}

extern "C" void kernel_launch(void* const* d_in, const int* in_sizes, int n_in,
                              void* d_out, int out_size, void* d_ws, size_t ws_size,
                              hipStream_t stream) {
  const float* X = (const float*)d_in[0];
  const int* bnd = (const int*)d_in[1];
  const float* Wif = (const float*)d_in[2];
  const float* Whf = (const float*)d_in[3];
  const float* bf_ = (const float*)d_in[4];
  const float* Wib = (const float*)d_in[5];
  const float* Whb = (const float*)d_in[6];
  const float* bb_ = (const float*)d_in[7];
  float* out = (float*)d_out;

  wr_bounds<<<1, 256, 0, stream>>>(bnd, out + 16777216);

  char* ws = (char*)d_ws;
  const size_t NEED = 176702464ULL;
  if (ws_size < NEED) return;

  unsigned short* XPb = (unsigned short*)(ws + 0);          // 128 MB
  unsigned short* Xb = (unsigned short*)(ws + 134217728);   // 32 MB
  unsigned short* Wc = (unsigned short*)(ws + 167772160);   // 8 MB
  float* biasp = (float*)(ws + 176160768);                  // 16 KB
  unsigned short* hb0 = (unsigned short*)(ws + 176177152);  // 256 KB
  unsigned short* hb1 = (unsigned short*)(ws + 176439296);  // 256 KB
  unsigned int* ctrp = (unsigned int*)(ws + 176701440);     // 1 KB (8 x 128B)

  cast_x<<<16384, 256, 0, stream>>>(X, Xb);
  pack_w<<<4096, 256, 0, stream>>>(Wif, bf_, Wib, bb_, Wc, biasp);
  dim3 gg(128, 32);
  gemm_xp<<<gg, 256, 0, stream>>>(Xb, Wc, biasp, XPb);

  hipMemsetAsync(hb0, 0, 262144, stream);
  hipMemsetAsync(ctrp, 0, 1024, stream);

  {
    const unsigned short* xpb = XPb;
    const float* whf = Whf;
    const float* whb = Whb;
    unsigned short* h0 = hb0;
    unsigned short* h1 = hb1;
    float* op = out;
    unsigned int* cp = ctrp;
    void* args[] = {&xpb, &whf, &whb, &h0, &h1, &op, &cp};
    hipError_t e = hipLaunchCooperativeKernel((const void*)lstm_persist, dim3(256), dim3(256),
                                              args, 0, stream);
    if (e != hipSuccess) {
      // fallback: plain launch; 256 blocks @ 1 block/CU on 256 CUs co-reside
      lstm_persist<<<256, 256, 0, stream>>>(XPb, Whf, Whb, hb0, hb1, out, ctrp);
    }
  }
}

// Round 5
// 543.006 us; speedup vs baseline: 10.5992x; 1.2428x over previous
//
#include <hip/hip_runtime.h>

// BiLSTM: T=16384 tokens = 128 segs x 128, D=1024, H=512, bidirectional.
//  1) cast X -> bf16; pack W_ih_f|W_ih_b -> bf16 [4096][1024]; bias concat.
//  2) MFMA GEMM: XP = X @ Wcat^T + bias. 128x128 tile, BK=64, T2 XOR-swizzle.
//  3) Persistent recurrence (cooperative): 256 blocks = (dir, cs: 16-chain set,
//     ut: 32-unit tile). W_hh slice [128 rows][512] bf16 resident in LDS
//     (128 KB). Full-K waves (no cross-wave reduction). Group = 16 blocks
//     sharing one chain-set; h exchanged via LLC-coherent (sc0|sc1) ops,
//     fence-free relaxed-counter barrier (proven in r4).
//  4) boundaries as floats to d_out tail.

typedef __attribute__((ext_vector_type(8))) short bf16x8;
typedef __attribute__((ext_vector_type(4))) float f32x4;

__device__ __forceinline__ unsigned short f2bf(float f) {
  unsigned int x = __builtin_bit_cast(unsigned int, f);
  x += 0x7fffu + ((x >> 16) & 1u);
  return (unsigned short)(x >> 16);
}
__device__ __forceinline__ float bf2f(unsigned short u) {
  unsigned int x = ((unsigned int)u) << 16;
  return __builtin_bit_cast(float, x);
}
__device__ __forceinline__ float sigm(float x) { return 1.f / (1.f + __expf(-x)); }
__device__ __forceinline__ float tanhfast(float x) {
  float e = __expf(2.f * x);
  return 1.f - 2.f / (e + 1.f);
}

__device__ __forceinline__ void gl_lds16(const void* g, void* l) {
  __builtin_amdgcn_global_load_lds((const __attribute__((address_space(1))) unsigned int*)g,
                                   (__attribute__((address_space(3))) unsigned int*)l, 16, 0, 0);
}
// LLC-coherent variant: aux = SC0|SC1 -> bypass L1/L2, read from LLC.
__device__ __forceinline__ void gl_lds16_llc(const void* g, void* l) {
  __builtin_amdgcn_global_load_lds((const __attribute__((address_space(1))) unsigned int*)g,
                                   (__attribute__((address_space(3))) unsigned int*)l, 16, 0, 17);
}

// ---------------- cast X to bf16 ----------------
__global__ __launch_bounds__(256) void cast_x(const float* __restrict__ X,
                                              unsigned short* __restrict__ Xb) {
  const int i = blockIdx.x * 256 + threadIdx.x;
  const float4 v = ((const float4*)X)[i];
  uint2 o;
  o.x = (unsigned int)f2bf(v.x) | ((unsigned int)f2bf(v.y) << 16);
  o.y = (unsigned int)f2bf(v.z) | ((unsigned int)f2bf(v.w) << 16);
  ((uint2*)Xb)[i] = o;
}

// ---------------- pack W_ih (concat dirs) to bf16 + bias ----------------
__global__ __launch_bounds__(256) void pack_w(const float* __restrict__ Wif,
                                              const float* __restrict__ bf_,
                                              const float* __restrict__ Wib,
                                              const float* __restrict__ bb_,
                                              unsigned short* __restrict__ Wc,
                                              float* __restrict__ biasp) {
  const int pr = blockIdx.x;  // 0..4095
  const int d = pr >> 11, r = pr & 2047;
  const float* src = (d ? Wib : Wif) + (size_t)r * 1024;
  const int t = threadIdx.x;
  const float4 v = ((const float4*)src)[t];
  uint2 o;
  o.x = (unsigned int)f2bf(v.x) | ((unsigned int)f2bf(v.y) << 16);
  o.y = (unsigned int)f2bf(v.z) | ((unsigned int)f2bf(v.w) << 16);
  ((uint2*)(Wc + (size_t)pr * 1024))[t] = o;
  if (t == 0) biasp[pr] = (d ? bb_ : bf_)[r];
}

// ---------------- MFMA GEMM: XP = Xb @ Wc^T + bias ----------------
// 128x128 tile, BK=64, both-sides XOR swizzle (linear LDS dest, inverse-
// swizzled global source, swizzled reads) -> conflict-free ds_read_b128.
__global__ __launch_bounds__(256) void gemm_xp(const unsigned short* __restrict__ A,
                                               const unsigned short* __restrict__ B,
                                               const float* __restrict__ bias,
                                               unsigned short* __restrict__ C) {
  __shared__ unsigned short As[128 * 64];  // 16 KB, rows of 128 B
  __shared__ unsigned short Bs[128 * 64];
  const int tid = threadIdx.x;
  const int lane = tid & 63;
  const int wid = tid >> 6;
  const int wm = wid >> 1, wn = wid & 1;
  const long brow = (long)blockIdx.x * 128;
  const long bcol = (long)blockIdx.y * 128;

  f32x4 acc[4][4];
  const f32x4 z = {0.f, 0.f, 0.f, 0.f};
#pragma unroll
  for (int i = 0; i < 4; ++i)
#pragma unroll
    for (int j = 0; j < 4; ++j) acc[i][j] = z;

  // staging geometry: byte o in tile -> row r=o>>7, col cb=o&127;
  // global source col = cb ^ ((r&7)<<4)  (inverse swizzle, 16B-preserving)
  int srow[4], scol[4];
#pragma unroll
  for (int j = 0; j < 4; ++j) {
    const int o = (j * 256 + tid) * 16;
    srow[j] = o >> 7;
    scol[j] = (o & 127) ^ ((srow[j] & 7) << 4);
  }

  for (int ks = 0; ks < 16; ++ks) {
    const int kb0 = ks * 128;  // K bytes
#pragma unroll
    for (int j = 0; j < 4; ++j) {
      const int o = (j * 256 + tid) * 16;
      gl_lds16((const char*)A + (brow + srow[j]) * 2048 + kb0 + scol[j], (char*)As + o);
      gl_lds16((const char*)B + (bcol + srow[j]) * 2048 + kb0 + scol[j], (char*)Bs + o);
    }
    __syncthreads();
    bf16x8 av[4][2], bv[4][2];
#pragma unroll
    for (int f = 0; f < 4; ++f) {
      const int ra = wm * 64 + f * 16 + (lane & 15);
      const int rb = wn * 64 + f * 16 + (lane & 15);
      const int swa = (ra & 7) << 4, swb = (rb & 7) << 4;
#pragma unroll
      for (int kk = 0; kk < 2; ++kk) {
        const int kby = kk * 64 + (lane >> 4) * 16;
        av[f][kk] = *(const bf16x8*)((const char*)As + ra * 128 + (kby ^ swa));
        bv[f][kk] = *(const bf16x8*)((const char*)Bs + rb * 128 + (kby ^ swb));
      }
    }
#pragma unroll
    for (int kk = 0; kk < 2; ++kk)
#pragma unroll
      for (int fm = 0; fm < 4; ++fm)
#pragma unroll
        for (int fn = 0; fn < 4; ++fn)
          acc[fm][fn] =
              __builtin_amdgcn_mfma_f32_16x16x32_bf16(av[fm][kk], bv[fn][kk], acc[fm][fn], 0, 0, 0);
    __syncthreads();
  }
  const int crow0 = wm * 64 + (lane >> 4) * 4;
  const int ccol0 = wn * 64 + (lane & 15);
#pragma unroll
  for (int fm = 0; fm < 4; ++fm) {
#pragma unroll
    for (int fn = 0; fn < 4; ++fn) {
      const long col = bcol + ccol0 + fn * 16;
      const float bsv = bias[col];
#pragma unroll
      for (int r = 0; r < 4; ++r) {
        const long row = brow + crow0 + fm * 16 + r;
        C[row * 4096 + col] = f2bf(acc[fm][fn][r] + bsv);
      }
    }
  }
}

// ---------------- persistent recurrence ----------------
// 256 blocks x 256 thr. bid = ut*16 + grp; grp = dir*8 + cs.
// Block: 16 chains (set cs), 32 units (tile ut), all 4 gates, full K=512.
// W_s: 128 rows x 512k bf16 (128 KB), row rl = w*32 + f*16 + p where
//   gate g = f*2 + (p>>3), unit_local ul = w*8 + (p&7); XOR-swizzled.
// Wave w (4 waves): units w*8..w*8+7, frag f: gates {2f, 2f+1}; full K.
// A_s: 16 chains x 512k bf16 (16 KB), staged per step from pre-swizzled
//   global hbuf via sc0|sc1 gl_lds. Gate combine: shfl_xor(8).
// Barrier: group = 16 blocks; relaxed counter, fence-free (r4 protocol).
__global__ __launch_bounds__(256, 1) void lstm_persist(
    const unsigned short* __restrict__ XPb, const float* __restrict__ Whf,
    const float* __restrict__ Whb, unsigned short* __restrict__ hb0,
    unsigned short* __restrict__ hb1, float* __restrict__ out,
    unsigned int* __restrict__ ctr) {
  __shared__ unsigned short W_s[65536];    // 128 KB
  __shared__ unsigned short A_s[8192];     // 16 KB
  __shared__ unsigned short Hrep[16][32];  // 1 KB

  const int tid = threadIdx.x;
  const int bid = blockIdx.x;
  const int ut = bid >> 4;    // 0..15 unit tile (32 units)
  const int grp = bid & 15;   // group id
  const int dir = grp >> 3;
  const int cs = grp & 7;     // chain-set (16 chains) within dir
  const int lane = tid & 63;
  const int w = tid >> 6;     // wave id
  const int p = lane & 15;
  const int hi = p >> 3;      // gate-pair half
  const int u_l = w * 8 + (p & 7);       // unit local 0..31
  const int u_g = ut * 32 + u_l;         // unit global 0..511
  unsigned int* const myctr = ctr + grp * 32;  // 128B stride

  // ---- W_hh slice -> LDS (bf16, swizzled), once. 2 threads/row. ----
  {
    const float* Wh = dir ? Whb : Whf;
    const int rl = tid >> 1;   // 0..127
    const int h2 = tid & 1;    // k-half of row
    const int ww = rl >> 5, ff = (rl >> 4) & 1, pp = rl & 15;
    const int g = ff * 2 + (pp >> 3);
    const int ul = ww * 8 + (pp & 7);
    const float* src = Wh + (size_t)(g * 512 + ut * 32 + ul) * 512 + h2 * 256;
    char* base = (char*)W_s + rl * 1024;
    const int sw = (rl & 7) << 4;
#pragma unroll
    for (int i = 0; i < 64; ++i) {
      const float4 v = ((const float4*)src)[i];
      const int kb = h2 * 512 + i * 8;
      uint2 o;
      o.x = (unsigned)f2bf(v.x) | ((unsigned)f2bf(v.y) << 16);
      o.y = (unsigned)f2bf(v.z) | ((unsigned)f2bf(v.w) << 16);
      *(uint2*)(base + (kb ^ sw)) = o;
    }
  }
  __syncthreads();

  float c_reg[2] = {0.f, 0.f};
  const size_t tileoff = (size_t)grp * 16384;  // bytes per group h tile (16 KB)
  const int cl0 = (lane >> 4) * 4 + 2 * hi;    // first of this lane's 2 chains

  for (int tau = 0; tau < 128; ++tau) {
    const unsigned short* hc = (tau & 1) ? hb1 : hb0;
    unsigned short* hn = (tau & 1) ? hb0 : hb1;
    const int tcol = dir ? (127 - tau) : tau;

    // stage h tile from LLC (pre-swizzled; linear 16 KB copy)
    {
      const char* srcb = (const char*)hc + tileoff;
      char* dstb = (char*)A_s;
#pragma unroll
      for (int j = 0; j < 4; ++j) {
        const int o = (j * 256 + tid) * 16;
        gl_lds16_llc(srcb + o, dstb + o);
      }
    }

    // XP prefetch into regs (all waves; consumed in gate phase)
    unsigned short xpr[2][4];
#pragma unroll
    for (int j = 0; j < 2; ++j) {
      const int seg = cs * 16 + cl0 + j;
      const size_t tok = (size_t)seg * 128 + tcol;
      const unsigned short* xp = XPb + tok * 4096 + dir * 2048 + u_g;
#pragma unroll
      for (int g = 0; g < 4; ++g) xpr[j][g] = xp[g * 512];
    }
    __syncthreads();  // A_s ready (drains vmcnt)

    // MFMA: full K=512; frag f=0 -> gates {0,1}, f=1 -> gates {2,3}
    f32x4 acc0, acc1;
    const f32x4 z = {0.f, 0.f, 0.f, 0.f};
    acc0 = z; acc1 = z;
    {
      const char* abase = (const char*)A_s + p * 1024;   // chain = p
      const int asw = (p & 7) << 4;
      const char* bbase = (const char*)W_s + (w * 32 + p) * 1024;
#pragma unroll
      for (int kk = 0; kk < 16; ++kk) {
        const int kb = kk * 64 + (lane >> 4) * 16;
        const bf16x8 af = *(const bf16x8*)(abase + (kb ^ asw));
        const bf16x8 bf0 = *(const bf16x8*)(bbase + (kb ^ asw));
        const bf16x8 bf1 = *(const bf16x8*)(bbase + 16384 + (kb ^ asw));
        acc0 = __builtin_amdgcn_mfma_f32_16x16x32_bf16(af, bf0, acc0, 0, 0, 0);
        acc1 = __builtin_amdgcn_mfma_f32_16x16x32_bf16(af, bf1, acc1, 0, 0, 0);
      }
    }

    // gate combine: lane p (hi=0) holds gates {0,2}, lane p^8 holds {1,3}
    // for all 4 chain-rows; exchange the other half's rows via shfl_xor(8).
    {
      const float s0 = hi ? acc0[0] : acc0[2];
      const float s1 = hi ? acc0[1] : acc0[3];
      const float s2 = hi ? acc1[0] : acc1[2];
      const float s3 = hi ? acc1[1] : acc1[3];
      const float e0 = __shfl_xor(s0, 8);
      const float e1 = __shfl_xor(s1, 8);
      const float e2 = __shfl_xor(s2, 8);
      const float e3 = __shfl_xor(s3, 8);
      const float a0 = hi ? acc0[2] : acc0[0];  // my acc0[r0]
      const float a1 = hi ? acc0[3] : acc0[1];
      const float b0 = hi ? acc1[2] : acc1[0];
      const float b1 = hi ? acc1[3] : acc1[1];
      // r = cl0 (j=0) and cl0+1 (j=1)
      const float gi[2] = {hi ? e0 : a0, hi ? e1 : a1};
      const float gf[2] = {hi ? a0 : e0, hi ? a1 : e1};
      const float gg[2] = {hi ? e2 : b0, hi ? e3 : b1};
      const float go[2] = {hi ? b0 : e2, hi ? b1 : e3};
#pragma unroll
      for (int j = 0; j < 2; ++j) {
        const int cl = cl0 + j;
        const int seg = cs * 16 + cl;
        const size_t tok = (size_t)seg * 128 + tcol;
        const float pi = gi[j] + bf2f(xpr[j][0]);
        const float pf = gf[j] + bf2f(xpr[j][1]);
        const float pg = gg[j] + bf2f(xpr[j][2]);
        const float po = go[j] + bf2f(xpr[j][3]);
        float cv = sigm(pf) * c_reg[j] + sigm(pi) * tanhfast(pg);
        c_reg[j] = cv;
        const float hv = sigm(po) * tanhfast(cv);
        out[tok * 1024 + dir * 512 + u_g] = hv;
        Hrep[cl][u_l] = f2bf(hv);
      }
    }
    __syncthreads();  // Hrep complete

    // packed 8B LLC-coherent h stores (swizzled dest, 8B-block preserving)
    if (tid < 128) {
      const int cl = tid >> 3, q = tid & 7;
      const unsigned long long v = *(const unsigned long long*)&Hrep[cl][q * 4];
      char* dst = (char*)hn + tileoff + cl * 1024 + ((ut * 64 + q * 8) ^ ((cl & 7) << 4));
      __hip_atomic_store((unsigned long long*)dst, v, __ATOMIC_RELAXED,
                         __HIP_MEMORY_SCOPE_AGENT);
    }

    // ---- per-group barrier (fence-free, r4 protocol) ----
    __syncthreads();  // drains vmcnt(0): sc1 stores are at LLC
    if (tid == 0) {
      const unsigned old =
          __hip_atomic_fetch_add(myctr, 1u, __ATOMIC_RELAXED, __HIP_MEMORY_SCOPE_AGENT);
      const unsigned tgt = (unsigned)(tau + 1) * 16u;
      if (old != tgt - 1u) {
        while (__hip_atomic_load(myctr, __ATOMIC_RELAXED, __HIP_MEMORY_SCOPE_AGENT) < tgt)
          __builtin_amdgcn_s_sleep(1);
      }
    }
    __syncthreads();
  }
}

// ---------------- boundaries passthrough ----------------
__global__ void wr_bounds(const int* __restrict__ b, float* __restrict__ o) {
  const int i = threadIdx.x;
  if (i < 129) o[i] = (float)b[i];
}

extern "C" void kernel_launch(void* const* d_in, const int* in_sizes, int n_in,
                              void* d_out, int out_size, void* d_ws, size_t ws_size,
                              hipStream_t stream) {
  const float* X = (const float*)d_in[0];
  const int* bnd = (const int*)d_in[1];
  const float* Wif = (const float*)d_in[2];
  const float* Whf = (const float*)d_in[3];
  const float* bf_ = (const float*)d_in[4];
  const float* Wib = (const float*)d_in[5];
  const float* Whb = (const float*)d_in[6];
  const float* bb_ = (const float*)d_in[7];
  float* out = (float*)d_out;

  wr_bounds<<<1, 256, 0, stream>>>(bnd, out + 16777216);

  char* ws = (char*)d_ws;
  const size_t NEED = 176703488ULL;
  if (ws_size < NEED) return;

  unsigned short* XPb = (unsigned short*)(ws + 0);          // 128 MB
  unsigned short* Xb = (unsigned short*)(ws + 134217728);   // 32 MB
  unsigned short* Wc = (unsigned short*)(ws + 167772160);   // 8 MB
  float* biasp = (float*)(ws + 176160768);                  // 16 KB
  unsigned short* hb0 = (unsigned short*)(ws + 176177152);  // 256 KB
  unsigned short* hb1 = (unsigned short*)(ws + 176439296);  // 256 KB
  unsigned int* ctrp = (unsigned int*)(ws + 176701440);     // 2 KB (16 x 128B)

  cast_x<<<16384, 256, 0, stream>>>(X, Xb);
  pack_w<<<4096, 256, 0, stream>>>(Wif, bf_, Wib, bb_, Wc, biasp);
  dim3 gg(128, 32);
  gemm_xp<<<gg, 256, 0, stream>>>(Xb, Wc, biasp, XPb);

  hipMemsetAsync(hb0, 0, 262144, stream);
  hipMemsetAsync(ctrp, 0, 2048, stream);

  {
    const unsigned short* xpb = XPb;
    const float* whf = Whf;
    const float* whb = Whb;
    unsigned short* h0 = hb0;
    unsigned short* h1 = hb1;
    float* op = out;
    unsigned int* cp = ctrp;
    void* args[] = {&xpb, &whf, &whb, &h0, &h1, &op, &cp};
    hipError_t e = hipLaunchCooperativeKernel((const void*)lstm_persist, dim3(256), dim3(256),
                                              args, 0, stream);
    if (e != hipSuccess) {
      lstm_persist<<<256, 256, 0, stream>>>(XPb, Whf, Whb, hb0, hb1, out, ctrp);
    }
  }
}